// Round 1
// baseline (43.734 us; speedup 1.0000x reference)
//
#include <hip/hip_runtime.h>

// B=2048, T=8192, fp32 in, scalar fp32 out.
// d_in[0]=target_angle [B,T], d_in[1]=target_class [B,3],
// d_in[2]=pred_angle [B,T], d_in[3]=pred_class [B,3]

#define CHUNK 2048          // elements of one row per block
#define NTHREADS 256        // 8 elements per thread

__global__ __launch_bounds__(NTHREADS) void wma_partial_kernel(
    const float* __restrict__ ta, const float* __restrict__ pa,
    float* __restrict__ partial, int T, int blocksPerRow)
{
    __shared__ float s[CHUNK + 4];

    const int row = blockIdx.x / blocksPerRow;
    const int seg = blockIdx.x % blocksPerRow;
    const long base = (long)row * T + (long)seg * CHUNK;
    const int t = threadIdx.x;

    // Main body: 8 contiguous floats per thread via two float4 loads per input.
    const float4* ta4 = (const float4*)(ta + base);
    const float4* pa4 = (const float4*)(pa + base);
    float4 a0 = ta4[2 * t];
    float4 a1 = ta4[2 * t + 1];
    float4 p0 = pa4[2 * t];
    float4 p1 = pa4[2 * t + 1];

    float* sp = s + 2 + t * 8;
    sp[0] = a0.x - p0.x;
    sp[1] = a0.y - p0.y;
    sp[2] = a0.z - p0.z;
    sp[3] = a0.w - p0.w;
    sp[4] = a1.x - p1.x;
    sp[5] = a1.y - p1.y;
    sp[6] = a1.z - p1.z;
    sp[7] = a1.w - p1.w;

    // Halo: +-2 around the chunk; zero outside the row (matches jnp.pad).
    if (t == 0) {
        const int col0 = seg * CHUNK;
        s[0] = (col0 - 2 >= 0) ? (ta[base - 2] - pa[base - 2]) : 0.0f;
        s[1] = (col0 - 1 >= 0) ? (ta[base - 1] - pa[base - 1]) : 0.0f;
    } else if (t == 1) {
        const int colE = seg * CHUNK + CHUNK;  // first column past the chunk
        s[CHUNK + 2] = (colE     < T) ? (ta[base + CHUNK]     - pa[base + CHUNK])     : 0.0f;
        s[CHUNK + 3] = (colE + 1 < T) ? (ta[base + CHUNK + 1] - pa[base + CHUNK + 1]) : 0.0f;
    }
    __syncthreads();

    float acc = 0.0f;
#pragma unroll
    for (int j = 0; j < 8; ++j) {
        const int idx = 2 + t * 8 + j;
        const float w = 0.05f * s[idx - 2] + 0.1f * s[idx - 1] + 0.7f * s[idx]
                      + 0.1f * s[idx + 1] + 0.05f * s[idx + 2];
        acc += w * w;
    }

    // Wave (64-lane) reduce, then cross-wave via LDS.
#pragma unroll
    for (int off = 32; off; off >>= 1) acc += __shfl_down(acc, off, 64);

    __shared__ float wsum[NTHREADS / 64];
    if ((t & 63) == 0) wsum[t >> 6] = acc;
    __syncthreads();
    if (t == 0) {
        float b = 0.0f;
#pragma unroll
        for (int i = 0; i < NTHREADS / 64; ++i) b += wsum[i];
        partial[blockIdx.x] = b;
    }
}

__global__ __launch_bounds__(NTHREADS) void finalize_kernel(
    const float* __restrict__ partial, int nPartial,
    const float* __restrict__ tc, const float* __restrict__ pc, int nClass,
    float* __restrict__ out)
{
    const int t = threadIdx.x;

    float sa = 0.0f;
    for (int i = t; i < nPartial; i += NTHREADS) sa += partial[i];

    float sc = 0.0f;
    for (int i = t; i < nClass; i += NTHREADS) {
        const float d = tc[i] - pc[i];
        sc += d * d;
    }

#pragma unroll
    for (int off = 32; off; off >>= 1) {
        sa += __shfl_down(sa, off, 64);
        sc += __shfl_down(sc, off, 64);
    }

    __shared__ float ra[NTHREADS / 64], rc[NTHREADS / 64];
    if ((t & 63) == 0) { ra[t >> 6] = sa; rc[t >> 6] = sc; }
    __syncthreads();
    if (t == 0) {
        float a = 0.0f, c = 0.0f;
#pragma unroll
        for (int i = 0; i < NTHREADS / 64; ++i) { a += ra[i]; c += rc[i]; }
        out[0] = 0.8f * a + 0.2f * c;
    }
}

extern "C" void kernel_launch(void* const* d_in, const int* in_sizes, int n_in,
                              void* d_out, int out_size, void* d_ws, size_t ws_size,
                              hipStream_t stream)
{
    const float* ta = (const float*)d_in[0];  // target_angle [B,T]
    const float* tc = (const float*)d_in[1];  // target_class [B,3]
    const float* pa = (const float*)d_in[2];  // pred_angle  [B,T]
    const float* pc = (const float*)d_in[3];  // pred_class  [B,3]
    float* out = (float*)d_out;

    const int nAngle = in_sizes[0];           // B*T
    const int nClass = in_sizes[1];           // B*3
    const int T = 8192;
    const int B = nAngle / T;
    const int blocksPerRow = T / CHUNK;       // 4
    const int grid = B * blocksPerRow;        // 8192

    float* partial = (float*)d_ws;            // grid floats (32 KB) < ws_size

    wma_partial_kernel<<<grid, NTHREADS, 0, stream>>>(ta, pa, partial, T, blocksPerRow);
    finalize_kernel<<<1, NTHREADS, 0, stream>>>(partial, grid, tc, pc, nClass, out);
}

// Round 2
// 43.121 us; speedup vs baseline: 1.0142x; 1.0142x over previous
//
#include <hip/hip_runtime.h>

// B=2048, T=8192, fp32 in, scalar fp32 out.
// d_in[0]=target_angle [B,T], d_in[1]=target_class [B,3],
// d_in[2]=pred_angle [B,T], d_in[3]=pred_class [B,3]
//
// Register-only 5-tap WMA: each thread owns 8 contiguous diffs; +-2 halo via
// wave shuffles; lanes 0/63 patch the wave boundary with direct global loads
// (L1-resident). No LDS staging -> no bank conflicts.

#define NTHREADS 256
#define PER_THREAD 8

__global__ __launch_bounds__(NTHREADS) void wma_partial_kernel(
    const float* __restrict__ ta, const float* __restrict__ pa,
    float* __restrict__ partial, int T)
{
    const int t = threadIdx.x;
    const long e = ((long)blockIdx.x * NTHREADS + t) * PER_THREAD;
    const int col = (int)(e % T);   // column of this thread's first element

    const float4* ta4 = (const float4*)(ta + e);
    const float4* pa4 = (const float4*)(pa + e);
    const float4 a0 = ta4[0], a1 = ta4[1];
    const float4 p0 = pa4[0], p1 = pa4[1];

    const float d0 = a0.x - p0.x, d1 = a0.y - p0.y, d2 = a0.z - p0.z, d3 = a0.w - p0.w;
    const float d4 = a1.x - p1.x, d5 = a1.y - p1.y, d6 = a1.z - p1.z, d7 = a1.w - p1.w;

    // Halo from neighbor lanes (element indices e-2, e-1, e+8, e+9).
    const int lane = t & 63;
    float dm2 = __shfl_up(d6, 1, 64);
    float dm1 = __shfl_up(d7, 1, 64);
    float dp8 = __shfl_down(d0, 1, 64);
    float dp9 = __shfl_down(d1, 1, 64);

    // Wave-edge lanes: fetch halo from global (zero outside the row = jnp.pad).
    if (lane == 0) {
        dm1 = (col >= 1) ? (ta[e - 1] - pa[e - 1]) : 0.0f;
        dm2 = (col >= 2) ? (ta[e - 2] - pa[e - 2]) : 0.0f;
    }
    if (lane == 63) {
        dp8 = (col + PER_THREAD     < T) ? (ta[e + 8] - pa[e + 8]) : 0.0f;
        dp9 = (col + PER_THREAD + 1 < T) ? (ta[e + 9] - pa[e + 9]) : 0.0f;
    }

    float acc = 0.0f, w;
    w = 0.05f*dm2 + 0.1f*dm1 + 0.7f*d0 + 0.1f*d1  + 0.05f*d2;  acc += w*w;
    w = 0.05f*dm1 + 0.1f*d0  + 0.7f*d1 + 0.1f*d2  + 0.05f*d3;  acc += w*w;
    w = 0.05f*d0  + 0.1f*d1  + 0.7f*d2 + 0.1f*d3  + 0.05f*d4;  acc += w*w;
    w = 0.05f*d1  + 0.1f*d2  + 0.7f*d3 + 0.1f*d4  + 0.05f*d5;  acc += w*w;
    w = 0.05f*d2  + 0.1f*d3  + 0.7f*d4 + 0.1f*d5  + 0.05f*d6;  acc += w*w;
    w = 0.05f*d3  + 0.1f*d4  + 0.7f*d5 + 0.1f*d6  + 0.05f*d7;  acc += w*w;
    w = 0.05f*d4  + 0.1f*d5  + 0.7f*d6 + 0.1f*d7  + 0.05f*dp8; acc += w*w;
    w = 0.05f*d5  + 0.1f*d6  + 0.7f*d7 + 0.1f*dp8 + 0.05f*dp9; acc += w*w;

    // Wave (64-lane) reduce, then cross-wave via tiny LDS.
#pragma unroll
    for (int off = 32; off; off >>= 1) acc += __shfl_down(acc, off, 64);

    __shared__ float wsum[NTHREADS / 64];
    if ((t & 63) == 0) wsum[t >> 6] = acc;
    __syncthreads();
    if (t == 0) {
        float b = 0.0f;
#pragma unroll
        for (int i = 0; i < NTHREADS / 64; ++i) b += wsum[i];
        partial[blockIdx.x] = b;
    }
}

__global__ __launch_bounds__(NTHREADS) void finalize_kernel(
    const float* __restrict__ partial, int nPartial,
    const float* __restrict__ tc, const float* __restrict__ pc, int nClass,
    float* __restrict__ out)
{
    const int t = threadIdx.x;

    float sa = 0.0f;
    for (int i = t; i < nPartial; i += NTHREADS) sa += partial[i];

    float sc = 0.0f;
    for (int i = t; i < nClass; i += NTHREADS) {
        const float d = tc[i] - pc[i];
        sc += d * d;
    }

#pragma unroll
    for (int off = 32; off; off >>= 1) {
        sa += __shfl_down(sa, off, 64);
        sc += __shfl_down(sc, off, 64);
    }

    __shared__ float ra[NTHREADS / 64], rc[NTHREADS / 64];
    if ((t & 63) == 0) { ra[t >> 6] = sa; rc[t >> 6] = sc; }
    __syncthreads();
    if (t == 0) {
        float a = 0.0f, c = 0.0f;
#pragma unroll
        for (int i = 0; i < NTHREADS / 64; ++i) { a += ra[i]; c += rc[i]; }
        out[0] = 0.8f * a + 0.2f * c;
    }
}

extern "C" void kernel_launch(void* const* d_in, const int* in_sizes, int n_in,
                              void* d_out, int out_size, void* d_ws, size_t ws_size,
                              hipStream_t stream)
{
    const float* ta = (const float*)d_in[0];  // target_angle [B,T]
    const float* tc = (const float*)d_in[1];  // target_class [B,3]
    const float* pa = (const float*)d_in[2];  // pred_angle  [B,T]
    const float* pc = (const float*)d_in[3];  // pred_class  [B,3]
    float* out = (float*)d_out;

    const int nAngle = in_sizes[0];           // B*T
    const int nClass = in_sizes[1];           // B*3
    const int T = 8192;
    const int grid = nAngle / (NTHREADS * PER_THREAD);  // 8192

    float* partial = (float*)d_ws;            // grid floats (32 KB) < ws_size

    wma_partial_kernel<<<grid, NTHREADS, 0, stream>>>(ta, pa, partial, T);
    finalize_kernel<<<1, NTHREADS, 0, stream>>>(partial, grid, tc, pc, nClass, out);
}

// Round 3
// 40.913 us; speedup vs baseline: 1.0689x; 1.0539x over previous
//
#include <hip/hip_runtime.h>

// B=2048, T=8192, fp32 in, scalar fp32 out.
// d_in[0]=target_angle [B,T], d_in[1]=target_class [B,3],
// d_in[2]=pred_angle [B,T], d_in[3]=pred_class [B,3]
//
// One block per row. Each thread owns 8 contiguous elements in each of 4
// segments (256 thr * 8 * 4 = 8192 = T). ALL 16 dwordx4 loads are issued
// up-front (16 KB in flight per wave) so each wave's memory round trip is
// amortized over 4x the work vs round-1/2. Halo via wave shuffles; edge
// lanes patch from global (L2-hit).

#define NTHREADS 256
#define SEGS 4
#define SEGSPAN (NTHREADS * 8)   // 2048 columns per segment

__global__ __launch_bounds__(NTHREADS) void wma_partial_kernel(
    const float* __restrict__ ta, const float* __restrict__ pa,
    float* __restrict__ partial, int T)
{
    const int t = threadIdx.x;
    const int lane = t & 63;
    const long rowBase = (long)blockIdx.x * T;

    // ---- issue all main loads up-front (16 x global_load_dwordx4) ----
    float4 A[SEGS][2], P[SEGS][2];
#pragma unroll
    for (int s = 0; s < SEGS; ++s) {
        const long e = rowBase + (long)s * SEGSPAN + (long)t * 8;
        const float4* ta4 = (const float4*)(ta + e);
        const float4* pa4 = (const float4*)(pa + e);
        A[s][0] = ta4[0]; A[s][1] = ta4[1];
        P[s][0] = pa4[0]; P[s][1] = pa4[1];
    }

    // ---- edge-lane halo loads (issued early too; L2-resident lines) ----
    float em2[SEGS], em1[SEGS], ep8[SEGS], ep9[SEGS];
#pragma unroll
    for (int s = 0; s < SEGS; ++s) { em2[s] = em1[s] = ep8[s] = ep9[s] = 0.0f; }
#pragma unroll
    for (int s = 0; s < SEGS; ++s) {
        const int col = s * SEGSPAN + t * 8;
        const long e = rowBase + col;
        if (lane == 0) {
            if (col >= 1) em1[s] = ta[e - 1] - pa[e - 1];
            if (col >= 2) em2[s] = ta[e - 2] - pa[e - 2];
        }
        if (lane == 63) {
            if (col + 8 < T) ep8[s] = ta[e + 8] - pa[e + 8];
            if (col + 9 < T) ep9[s] = ta[e + 9] - pa[e + 9];
        }
    }

    // ---- compute: 5-tap WMA of diff, squared, accumulated ----
    float acc = 0.0f;
#pragma unroll
    for (int s = 0; s < SEGS; ++s) {
        const float d0 = A[s][0].x - P[s][0].x;
        const float d1 = A[s][0].y - P[s][0].y;
        const float d2 = A[s][0].z - P[s][0].z;
        const float d3 = A[s][0].w - P[s][0].w;
        const float d4 = A[s][1].x - P[s][1].x;
        const float d5 = A[s][1].y - P[s][1].y;
        const float d6 = A[s][1].z - P[s][1].z;
        const float d7 = A[s][1].w - P[s][1].w;

        float dm2 = __shfl_up(d6, 1, 64);
        float dm1 = __shfl_up(d7, 1, 64);
        float dp8 = __shfl_down(d0, 1, 64);
        float dp9 = __shfl_down(d1, 1, 64);
        if (lane == 0)  { dm2 = em2[s]; dm1 = em1[s]; }
        if (lane == 63) { dp8 = ep8[s]; dp9 = ep9[s]; }

        float w;
        w = 0.05f*dm2 + 0.1f*dm1 + 0.7f*d0 + 0.1f*d1  + 0.05f*d2;  acc += w*w;
        w = 0.05f*dm1 + 0.1f*d0  + 0.7f*d1 + 0.1f*d2  + 0.05f*d3;  acc += w*w;
        w = 0.05f*d0  + 0.1f*d1  + 0.7f*d2 + 0.1f*d3  + 0.05f*d4;  acc += w*w;
        w = 0.05f*d1  + 0.1f*d2  + 0.7f*d3 + 0.1f*d4  + 0.05f*d5;  acc += w*w;
        w = 0.05f*d2  + 0.1f*d3  + 0.7f*d4 + 0.1f*d5  + 0.05f*d6;  acc += w*w;
        w = 0.05f*d3  + 0.1f*d4  + 0.7f*d5 + 0.1f*d6  + 0.05f*d7;  acc += w*w;
        w = 0.05f*d4  + 0.1f*d5  + 0.7f*d6 + 0.1f*d7  + 0.05f*dp8; acc += w*w;
        w = 0.05f*d5  + 0.1f*d6  + 0.7f*d7 + 0.1f*dp8 + 0.05f*dp9; acc += w*w;
    }

    // ---- wave reduce, then cross-wave via tiny LDS ----
#pragma unroll
    for (int off = 32; off; off >>= 1) acc += __shfl_down(acc, off, 64);

    __shared__ float wsum[NTHREADS / 64];
    if ((t & 63) == 0) wsum[t >> 6] = acc;
    __syncthreads();
    if (t == 0) {
        float b = 0.0f;
#pragma unroll
        for (int i = 0; i < NTHREADS / 64; ++i) b += wsum[i];
        partial[blockIdx.x] = b;
    }
}

__global__ __launch_bounds__(NTHREADS) void finalize_kernel(
    const float* __restrict__ partial, int nPartial,
    const float* __restrict__ tc, const float* __restrict__ pc, int nClass,
    float* __restrict__ out)
{
    const int t = threadIdx.x;

    float sa = 0.0f;
    for (int i = t; i < nPartial; i += NTHREADS) sa += partial[i];

    float sc = 0.0f;
    for (int i = t; i < nClass; i += NTHREADS) {
        const float d = tc[i] - pc[i];
        sc += d * d;
    }

#pragma unroll
    for (int off = 32; off; off >>= 1) {
        sa += __shfl_down(sa, off, 64);
        sc += __shfl_down(sc, off, 64);
    }

    __shared__ float ra[NTHREADS / 64], rc[NTHREADS / 64];
    if ((t & 63) == 0) { ra[t >> 6] = sa; rc[t >> 6] = sc; }
    __syncthreads();
    if (t == 0) {
        float a = 0.0f, c = 0.0f;
#pragma unroll
        for (int i = 0; i < NTHREADS / 64; ++i) { a += ra[i]; c += rc[i]; }
        out[0] = 0.8f * a + 0.2f * c;
    }
}

extern "C" void kernel_launch(void* const* d_in, const int* in_sizes, int n_in,
                              void* d_out, int out_size, void* d_ws, size_t ws_size,
                              hipStream_t stream)
{
    const float* ta = (const float*)d_in[0];  // target_angle [B,T]
    const float* tc = (const float*)d_in[1];  // target_class [B,3]
    const float* pa = (const float*)d_in[2];  // pred_angle  [B,T]
    const float* pc = (const float*)d_in[3];  // pred_class  [B,3]
    float* out = (float*)d_out;

    const int nAngle = in_sizes[0];           // B*T
    const int nClass = in_sizes[1];           // B*3
    const int T = 8192;
    const int B = nAngle / T;                 // 2048 blocks, one per row

    float* partial = (float*)d_ws;            // B floats (8 KB) < ws_size

    wma_partial_kernel<<<B, NTHREADS, 0, stream>>>(ta, pa, partial, T);
    finalize_kernel<<<1, NTHREADS, 0, stream>>>(partial, B, tc, pc, nClass, out);
}

// Round 5
// 38.042 us; speedup vs baseline: 1.1496x; 1.0755x over previous
//
#include <hip/hip_runtime.h>

// B=2048, T=8192, fp32 in, scalar fp32 out.
// d_in[0]=target_angle [B,T], d_in[1]=target_class [B,3],
// d_in[2]=pred_angle [B,T], d_in[3]=pred_class [B,3]
//
// Round-2 shape (8192 blocks, 4 KB one-shot per wave) with NON-TEMPORAL
// loads on the two read-once 64 MB streams to test whether the ~3.4 TB/s
// read cap is an L2-allocate-policy effect. Uses a plain ext_vector_type
// alias because __builtin_nontemporal_load rejects HIP_vector_type.

#define NTHREADS 256
#define PER_THREAD 8

typedef float f32x4 __attribute__((ext_vector_type(4)));

__global__ __launch_bounds__(NTHREADS) void wma_partial_kernel(
    const float* __restrict__ ta, const float* __restrict__ pa,
    float* __restrict__ partial, int T)
{
    const int t = threadIdx.x;
    const long e = ((long)blockIdx.x * NTHREADS + t) * PER_THREAD;
    const int col = (int)(e % T);   // column of this thread's first element

    const f32x4* ta4 = (const f32x4*)(ta + e);
    const f32x4* pa4 = (const f32x4*)(pa + e);
    const f32x4 a0 = __builtin_nontemporal_load(ta4);
    const f32x4 a1 = __builtin_nontemporal_load(ta4 + 1);
    const f32x4 p0 = __builtin_nontemporal_load(pa4);
    const f32x4 p1 = __builtin_nontemporal_load(pa4 + 1);

    const float d0 = a0.x - p0.x, d1 = a0.y - p0.y, d2 = a0.z - p0.z, d3 = a0.w - p0.w;
    const float d4 = a1.x - p1.x, d5 = a1.y - p1.y, d6 = a1.z - p1.z, d7 = a1.w - p1.w;

    // Halo from neighbor lanes (element indices e-2, e-1, e+8, e+9).
    const int lane = t & 63;
    float dm2 = __shfl_up(d6, 1, 64);
    float dm1 = __shfl_up(d7, 1, 64);
    float dp8 = __shfl_down(d0, 1, 64);
    float dp9 = __shfl_down(d1, 1, 64);

    // Wave-edge lanes: fetch halo from global (zero outside the row = jnp.pad).
    if (lane == 0) {
        dm1 = (col >= 1) ? (ta[e - 1] - pa[e - 1]) : 0.0f;
        dm2 = (col >= 2) ? (ta[e - 2] - pa[e - 2]) : 0.0f;
    }
    if (lane == 63) {
        dp8 = (col + PER_THREAD     < T) ? (ta[e + 8] - pa[e + 8]) : 0.0f;
        dp9 = (col + PER_THREAD + 1 < T) ? (ta[e + 9] - pa[e + 9]) : 0.0f;
    }

    float acc = 0.0f, w;
    w = 0.05f*dm2 + 0.1f*dm1 + 0.7f*d0 + 0.1f*d1  + 0.05f*d2;  acc += w*w;
    w = 0.05f*dm1 + 0.1f*d0  + 0.7f*d1 + 0.1f*d2  + 0.05f*d3;  acc += w*w;
    w = 0.05f*d0  + 0.1f*d1  + 0.7f*d2 + 0.1f*d3  + 0.05f*d4;  acc += w*w;
    w = 0.05f*d1  + 0.1f*d2  + 0.7f*d3 + 0.1f*d4  + 0.05f*d5;  acc += w*w;
    w = 0.05f*d2  + 0.1f*d3  + 0.7f*d4 + 0.1f*d5  + 0.05f*d6;  acc += w*w;
    w = 0.05f*d3  + 0.1f*d4  + 0.7f*d5 + 0.1f*d6  + 0.05f*d7;  acc += w*w;
    w = 0.05f*d4  + 0.1f*d5  + 0.7f*d6 + 0.1f*d7  + 0.05f*dp8; acc += w*w;
    w = 0.05f*d5  + 0.1f*d6  + 0.7f*d7 + 0.1f*dp8 + 0.05f*dp9; acc += w*w;

    // Wave (64-lane) reduce, then cross-wave via tiny LDS.
#pragma unroll
    for (int off = 32; off; off >>= 1) acc += __shfl_down(acc, off, 64);

    __shared__ float wsum[NTHREADS / 64];
    if ((t & 63) == 0) wsum[t >> 6] = acc;
    __syncthreads();
    if (t == 0) {
        float b = 0.0f;
#pragma unroll
        for (int i = 0; i < NTHREADS / 64; ++i) b += wsum[i];
        partial[blockIdx.x] = b;
    }
}

#define FIN_THREADS 1024

__global__ __launch_bounds__(FIN_THREADS) void finalize_kernel(
    const float* __restrict__ partial, int nPartial,
    const float* __restrict__ tc, const float* __restrict__ pc, int nClass,
    float* __restrict__ out)
{
    const int t = threadIdx.x;

    float sa = 0.0f;
    for (int i = t; i < nPartial; i += FIN_THREADS) sa += partial[i];

    float sc = 0.0f;
    for (int i = t; i < nClass; i += FIN_THREADS) {
        const float d = tc[i] - pc[i];
        sc += d * d;
    }

#pragma unroll
    for (int off = 32; off; off >>= 1) {
        sa += __shfl_down(sa, off, 64);
        sc += __shfl_down(sc, off, 64);
    }

    __shared__ float ra[FIN_THREADS / 64], rc[FIN_THREADS / 64];
    if ((t & 63) == 0) { ra[t >> 6] = sa; rc[t >> 6] = sc; }
    __syncthreads();
    if (t == 0) {
        float a = 0.0f, c = 0.0f;
#pragma unroll
        for (int i = 0; i < FIN_THREADS / 64; ++i) { a += ra[i]; c += rc[i]; }
        out[0] = 0.8f * a + 0.2f * c;
    }
}

extern "C" void kernel_launch(void* const* d_in, const int* in_sizes, int n_in,
                              void* d_out, int out_size, void* d_ws, size_t ws_size,
                              hipStream_t stream)
{
    const float* ta = (const float*)d_in[0];  // target_angle [B,T]
    const float* tc = (const float*)d_in[1];  // target_class [B,3]
    const float* pa = (const float*)d_in[2];  // pred_angle  [B,T]
    const float* pc = (const float*)d_in[3];  // pred_class  [B,3]
    float* out = (float*)d_out;

    const int nAngle = in_sizes[0];           // B*T
    const int nClass = in_sizes[1];           // B*3
    const int T = 8192;
    const int grid = nAngle / (NTHREADS * PER_THREAD);  // 8192

    float* partial = (float*)d_ws;            // grid floats (32 KB) < ws_size

    wma_partial_kernel<<<grid, NTHREADS, 0, stream>>>(ta, pa, partial, T);
    finalize_kernel<<<1, FIN_THREADS, 0, stream>>>(partial, grid, tc, pc, nClass, out);
}

// Round 6
// 36.790 us; speedup vs baseline: 1.1887x; 1.0340x over previous
//
#include <hip/hip_runtime.h>

// B=2048, T=8192, fp32 in, scalar fp32 out.
// d_in[0]=target_angle [B,T], d_in[1]=target_class [B,3],
// d_in[2]=pred_angle [B,T], d_in[3]=pred_class [B,3]
//
// 2048 blocks; each thread owns 8 contiguous elements in each of 4 grid-sweep
// chunks. All 16 nt dwordx4 loads (16 KB/wave) issued up-front; one reduce
// tail per wave amortized over 4x the data. Halo via wave shuffles; edge
// lanes patch from global, loads hoisted into the issue phase.

#define NTHREADS 256
#define CHUNKS 4

typedef float f32x4 __attribute__((ext_vector_type(4)));

__global__ __launch_bounds__(NTHREADS) void wma_partial_kernel(
    const float* __restrict__ ta, const float* __restrict__ pa,
    float* __restrict__ partial, int T)
{
    const int t = threadIdx.x;
    const int lane = t & 63;
    const long span = (long)gridDim.x * NTHREADS * 8;   // elements per sweep
    const long base = ((long)blockIdx.x * NTHREADS + t) * 8;
    const int col = (int)(base % T);  // span % T == 0 -> same col every chunk

    // ---- issue all main loads up-front (16 x global_load_dwordx4 nt) ----
    f32x4 A[CHUNKS][2], P[CHUNKS][2];   // fully unrolled -> static indexing
#pragma unroll
    for (int c = 0; c < CHUNKS; ++c) {
        const float* tap = ta + base + (long)c * span;
        const float* pap = pa + base + (long)c * span;
        A[c][0] = __builtin_nontemporal_load((const f32x4*)tap);
        A[c][1] = __builtin_nontemporal_load((const f32x4*)tap + 1);
        P[c][0] = __builtin_nontemporal_load((const f32x4*)pap);
        P[c][1] = __builtin_nontemporal_load((const f32x4*)pap + 1);
    }

    // ---- edge-lane halo loads, hoisted into the issue phase ----
    // lane-0 cols are multiples of 512 -> col>0 implies col>=2.
    // lane-63 first-elem col ends a 512-group -> col+8<T implies col+9<T.
    float em1[CHUNKS], em2[CHUNKS], ep8[CHUNKS], ep9[CHUNKS];
#pragma unroll
    for (int c = 0; c < CHUNKS; ++c) { em1[c] = em2[c] = ep8[c] = ep9[c] = 0.0f; }
    if (lane == 0 && col > 0) {
#pragma unroll
        for (int c = 0; c < CHUNKS; ++c) {
            const long e = base + (long)c * span;
            em1[c] = ta[e - 1] - pa[e - 1];
            em2[c] = ta[e - 2] - pa[e - 2];
        }
    }
    if (lane == 63 && col + 8 < T) {
#pragma unroll
        for (int c = 0; c < CHUNKS; ++c) {
            const long e = base + (long)c * span;
            ep8[c] = ta[e + 8] - pa[e + 8];
            ep9[c] = ta[e + 9] - pa[e + 9];
        }
    }

    // ---- compute: 5-tap WMA of diff, squared, accumulated ----
    float acc = 0.0f;
#pragma unroll
    for (int c = 0; c < CHUNKS; ++c) {
        const float d0 = A[c][0].x - P[c][0].x;
        const float d1 = A[c][0].y - P[c][0].y;
        const float d2 = A[c][0].z - P[c][0].z;
        const float d3 = A[c][0].w - P[c][0].w;
        const float d4 = A[c][1].x - P[c][1].x;
        const float d5 = A[c][1].y - P[c][1].y;
        const float d6 = A[c][1].z - P[c][1].z;
        const float d7 = A[c][1].w - P[c][1].w;

        float dm2 = __shfl_up(d6, 1, 64);
        float dm1 = __shfl_up(d7, 1, 64);
        float dp8 = __shfl_down(d0, 1, 64);
        float dp9 = __shfl_down(d1, 1, 64);
        if (lane == 0)  { dm2 = em2[c]; dm1 = em1[c]; }
        if (lane == 63) { dp8 = ep8[c]; dp9 = ep9[c]; }

        float w;
        w = 0.05f*dm2 + 0.1f*dm1 + 0.7f*d0 + 0.1f*d1  + 0.05f*d2;  acc += w*w;
        w = 0.05f*dm1 + 0.1f*d0  + 0.7f*d1 + 0.1f*d2  + 0.05f*d3;  acc += w*w;
        w = 0.05f*d0  + 0.1f*d1  + 0.7f*d2 + 0.1f*d3  + 0.05f*d4;  acc += w*w;
        w = 0.05f*d1  + 0.1f*d2  + 0.7f*d3 + 0.1f*d4  + 0.05f*d5;  acc += w*w;
        w = 0.05f*d2  + 0.1f*d3  + 0.7f*d4 + 0.1f*d5  + 0.05f*d6;  acc += w*w;
        w = 0.05f*d3  + 0.1f*d4  + 0.7f*d5 + 0.1f*d6  + 0.05f*d7;  acc += w*w;
        w = 0.05f*d4  + 0.1f*d5  + 0.7f*d6 + 0.1f*d7  + 0.05f*dp8; acc += w*w;
        w = 0.05f*d5  + 0.1f*d6  + 0.7f*d7 + 0.1f*dp8 + 0.05f*dp9; acc += w*w;
    }

    // ---- one wave reduce per 16 KB, then cross-wave via tiny LDS ----
#pragma unroll
    for (int off = 32; off; off >>= 1) acc += __shfl_down(acc, off, 64);

    __shared__ float wsum[NTHREADS / 64];
    if ((t & 63) == 0) wsum[t >> 6] = acc;
    __syncthreads();
    if (t == 0) {
        float b = 0.0f;
#pragma unroll
        for (int i = 0; i < NTHREADS / 64; ++i) b += wsum[i];
        partial[blockIdx.x] = b;
    }
}

#define FIN_THREADS 1024

__global__ __launch_bounds__(FIN_THREADS) void finalize_kernel(
    const float* __restrict__ partial, int nPartial,
    const float* __restrict__ tc, const float* __restrict__ pc, int nClass,
    float* __restrict__ out)
{
    const int t = threadIdx.x;

    float sa = 0.0f;
    for (int i = t; i < nPartial; i += FIN_THREADS) sa += partial[i];

    float sc = 0.0f;
    for (int i = t; i < nClass; i += FIN_THREADS) {
        const float d = tc[i] - pc[i];
        sc += d * d;
    }

#pragma unroll
    for (int off = 32; off; off >>= 1) {
        sa += __shfl_down(sa, off, 64);
        sc += __shfl_down(sc, off, 64);
    }

    __shared__ float ra[FIN_THREADS / 64], rc[FIN_THREADS / 64];
    if ((t & 63) == 0) { ra[t >> 6] = sa; rc[t >> 6] = sc; }
    __syncthreads();
    if (t == 0) {
        float a = 0.0f, c = 0.0f;
#pragma unroll
        for (int i = 0; i < FIN_THREADS / 64; ++i) { a += ra[i]; c += rc[i]; }
        out[0] = 0.8f * a + 0.2f * c;
    }
}

extern "C" void kernel_launch(void* const* d_in, const int* in_sizes, int n_in,
                              void* d_out, int out_size, void* d_ws, size_t ws_size,
                              hipStream_t stream)
{
    const float* ta = (const float*)d_in[0];  // target_angle [B,T]
    const float* tc = (const float*)d_in[1];  // target_class [B,3]
    const float* pa = (const float*)d_in[2];  // pred_angle  [B,T]
    const float* pc = (const float*)d_in[3];  // pred_class  [B,3]
    float* out = (float*)d_out;

    const int nAngle = in_sizes[0];           // B*T
    const int nClass = in_sizes[1];           // B*3
    const int T = 8192;
    const int grid = nAngle / (NTHREADS * 8 * CHUNKS);  // 2048

    float* partial = (float*)d_ws;            // grid floats (8 KB) < ws_size

    wma_partial_kernel<<<grid, NTHREADS, 0, stream>>>(ta, pa, partial, T);
    finalize_kernel<<<1, FIN_THREADS, 0, stream>>>(partial, grid, tc, pc, nClass, out);
}